// Round 9
// baseline (605.033 us; speedup 1.0000x reference)
//
#include <hip/hip_runtime.h>
#include <cstdint>
#include <cstddef>

#define N_NODES 50000
#define E_EDGES 800000
#define IN_F    128
#define PCOLS   512   // P: [0,96) Y0 | [96,192) Zpre | [192,288) Zblk | [288,480) Zpost | pad

typedef unsigned short ushortT;
typedef unsigned int   uintT;
typedef __attribute__((ext_vector_type(8))) short s8v;   // 8 bf16 (4 VGPR)
typedef __attribute__((ext_vector_type(4))) float f4v;   // 4 fp32 (ext-vector: OK for nontemporal builtins)

__device__ __forceinline__ float bflo(uintT u){ union{uintT i;float f;}c; c.i=u<<16; return c.f; }
__device__ __forceinline__ float bfhi(uintT u){ union{uintT i;float f;}c; c.i=u&0xFFFF0000u; return c.f; }
__device__ __forceinline__ ushortT f2bfu(float f){
    union{float f;uintT u;}c; c.f=f;
    uintT r = c.u + 0x7FFF + ((c.u>>16)&1);
    return (ushortT)(r>>16);
}
__device__ __forceinline__ uintT pack2(float a, float b){
    return (uintT)f2bfu(a) | ((uintT)f2bfu(b) << 16);
}
__device__ __forceinline__ float rdlanef(float v, int sl){
    return __int_as_float(__builtin_amdgcn_readlane(__float_as_int(v), sl));
}

// ---------- pack weights: Wb [512][128] bf16, bcat[512] fp32,
//            Wt1 [3][32][32] (W_blk^T), Wt2 [3][64][32] (W_post^T) ----------
__global__ void pack_weights(const float* __restrict__ Wp,  const float* __restrict__ bp,
                             const float* __restrict__ Tp,  const float* __restrict__ bTp,
                             const float* __restrict__ Tb,  const float* __restrict__ bTb,
                             const float* __restrict__ Tpo, const float* __restrict__ bTpo,
                             const float* __restrict__ Wblk, const float* __restrict__ Wpost,
                             ushortT* __restrict__ Wb, float* __restrict__ bcat,
                             float* __restrict__ Wt1, float* __restrict__ Wt2)
{
    int id = blockIdx.x * 256 + threadIdx.x;
    if (id >= IN_F * PCOLS) return;
    int k = id >> 9;
    int c = id & 511;
    float v;
    if      (c < 96)  v = Wp [k*96  + c];
    else if (c < 192) v = Tp [k*96  + (c-96)];
    else if (c < 288) v = Tb [k*96  + (c-192)];
    else if (c < 480) v = Tpo[k*192 + (c-288)];
    else              v = 0.f;
    Wb[(size_t)c*IN_F + k] = f2bfu(v);
    if (k == 0) {
        float b;
        if      (c < 96)  b = bp  [c];
        else if (c < 192) b = bTp [c-96];
        else if (c < 288) b = bTb [c-192];
        else if (c < 480) b = bTpo[c-288];
        else              b = 0.f;
        bcat[c] = b;
    }
    if (id < 3*32*32) {              // Wblk[w][i][j] -> Wt1[(w*32+j)*32+i]
        int w = id >> 10, r = id & 1023;
        int i = r >> 5, j = r & 31;
        Wt1[(w*32 + j)*32 + i] = Wblk[id];
    }
    if (id < 3*32*64) {              // Wpost[w][i][j] -> Wt2[(w*64+j)*32+i]
        int w = id >> 11, r = id & 2047;
        int i = r >> 6, j = r & 63;
        Wt2[(w*64 + j)*32 + i] = Wpost[id];
    }
}

// ---------- convert data fp32 -> Ab bf16 [N][128] ----------
__global__ void convert_data(const float* __restrict__ A, ushortT* __restrict__ Ab)
{
    int gid = blockIdx.x * 256 + threadIdx.x;
    size_t off = (size_t)gid * 8;
    float4 v0 = *(const float4*)(A + off);
    float4 v1 = *(const float4*)(A + off + 4);
    uint4 u;
    u.x = pack2(v0.x, v0.y); u.y = pack2(v0.z, v0.w);
    u.z = pack2(v1.x, v1.y); u.w = pack2(v1.z, v1.w);
    *(uint4*)(Ab + off) = u;
}

// ---------- row_ptr via binary search on sorted tgt ----------
__global__ void build_row_ptr(const int* __restrict__ tgt, int* __restrict__ row_ptr,
                              int E, int Np1)
{
    int t = blockIdx.x * 256 + threadIdx.x;
    if (t >= Np1) return;
    int lo = 0, hi = E;
    while (lo < hi) {
        int mid = (lo + hi) >> 1;
        if (tgt[mid] < t) lo = mid + 1; else hi = mid;
    }
    row_ptr[t] = lo;
}

// ---------- srcpT[t][eg][s] = edge index for slot 8s+eg (or N if past deg); zero pad rows ----------
__global__ void build_srcp(const int* __restrict__ src, const int* __restrict__ row_ptr,
                           int* __restrict__ srcpT,
                           ushortT* __restrict__ Y0s, ushortT* __restrict__ rb1s,
                           ushortT* __restrict__ rb2s)
{
    int gid = blockIdx.x * 256 + threadIdx.x;   // N*64 threads
    int t = gid >> 6, slot = gid & 63;
    int lo = row_ptr[t];
    int deg = row_ptr[t+1] - lo;
    int v = slot < deg ? src[lo + slot] : N_NODES;
    srcpT[t*64 + (slot & 7)*8 + (slot >> 3)] = v;
    if (gid < 96) {     // zero dummy row N of each group slice of each stage
        int w = gid >> 5, k = gid & 31;
        Y0s [((size_t)w*(N_NODES+1) + N_NODES)*32 + k] = 0;
        rb1s[((size_t)w*(N_NODES+1) + N_NODES)*32 + k] = 0;
        rb2s[((size_t)w*(N_NODES+1) + N_NODES)*32 + k] = 0;
    }
}

// ---------- MFMA GEMM: P[M,512] = Ab[M,128] @ Wb^T + bcat ; also emit Y0s (group-split bf16) ----------
__global__ __launch_bounds__(256, 2) void gemm_mfma(const ushortT* __restrict__ Ab,
                                                    const ushortT* __restrict__ Wb,
                                                    const float* __restrict__ bcat,
                                                    float* __restrict__ P,
                                                    ushortT* __restrict__ Y0s, int M)
{
    __shared__ ushortT Asl[128][72];
    __shared__ ushortT Bsl[128][72];
    int tid = threadIdx.x;
    int nb = blockIdx.x * 128;
    int mb = blockIdx.y * 128;
    int wv = tid >> 6, lane = tid & 63;
    int wm = wv >> 1, wn = wv & 1;
    int cl = lane & 15, q = lane >> 4;

    f4v acc[4][4];
    #pragma unroll
    for (int i = 0; i < 4; ++i)
        #pragma unroll
        for (int j = 0; j < 4; ++j) acc[i][j] = (f4v)0.f;

    for (int kt = 0; kt < IN_F; kt += 64) {
        if (kt) __syncthreads();
        #pragma unroll
        for (int r = 0; r < 4; ++r) {
            int idx = tid + 256*r;
            int row = idx >> 3, qq = idx & 7;
            int gm = mb + row;
            uint4 v = make_uint4(0,0,0,0);
            if (gm < M) v = *(const uint4*)(Ab + (size_t)gm*IN_F + kt + qq*8);
            *(uint4*)(&Asl[row][qq*8]) = v;
        }
        #pragma unroll
        for (int r = 0; r < 4; ++r) {
            int idx = tid + 256*r;
            int row = idx >> 3, qq = idx & 7;
            uint4 v = *(const uint4*)(Wb + (size_t)(nb+row)*IN_F + kt + qq*8);
            *(uint4*)(&Bsl[row][qq*8]) = v;
        }
        __syncthreads();
        #pragma unroll
        for (int ks = 0; ks < 2; ++ks) {
            int ko = ks*32 + q*8;
            s8v af[4], bf[4];
            #pragma unroll
            for (int mt = 0; mt < 4; ++mt)
                af[mt] = *(const s8v*)(&Asl[wm*64 + mt*16 + cl][ko]);
            #pragma unroll
            for (int nt = 0; nt < 4; ++nt)
                bf[nt] = *(const s8v*)(&Bsl[wn*64 + nt*16 + cl][ko]);
            #pragma unroll
            for (int mt = 0; mt < 4; ++mt)
                #pragma unroll
                for (int nt = 0; nt < 4; ++nt)
                    acc[mt][nt] = __builtin_amdgcn_mfma_f32_16x16x32_bf16(af[mt], bf[nt], acc[mt][nt], 0, 0, 0);
        }
    }

    bool y0blk = (nb == 0) && (wn == 0);
    #pragma unroll
    for (int nt = 0; nt < 4; ++nt) {
        int gn = nb + wn*64 + nt*16 + cl;
        float bv = bcat[gn];
        bool doY = y0blk && (gn < 96);
        int wgrp = gn >> 5, kcol = gn & 31;
        #pragma unroll
        for (int mt = 0; mt < 4; ++mt) {
            int gm0 = mb + wm*64 + mt*16 + q*4;
            #pragma unroll
            for (int r = 0; r < 4; ++r) {
                int gm = gm0 + r;
                if (gm < M) {
                    float val = acc[mt][nt][r] + bv;
                    P[(size_t)gm*PCOLS + gn] = val;
                    if (doY) Y0s[((size_t)wgrp*(N_NODES+1) + gm)*32 + kcol] = f2bfu(val);
                }
            }
        }
    }
}

// ===== gather core: 32-feat (64 B) rows, 8 edges per load instr, single window =====
__device__ __forceinline__ void gather32(const ushortT* __restrict__ Xb,
                                         const int* __restrict__ srcpT,
                                         const int* __restrict__ src,
                                         int t, int lo, int deg, int lane,
                                         float& a0, float& a1, float& a2, float& a3)
{
    int eg = lane >> 3, li = lane & 7;
    // 8 indices for this lane's edge-group: srcpT[t][eg][0..8)
    int4 iva = *(const int4*)(srcpT + t*64 + eg*8);
    int4 ivb = *(const int4*)(srcpT + t*64 + eg*8 + 4);
    int iv[8] = {iva.x, iva.y, iva.z, iva.w, ivb.x, ivb.y, ivb.z, ivb.w};
    uint2 u[8];
    #pragma unroll
    for (int s = 0; s < 8; ++s)
        u[s] = *(const uint2*)(Xb + (size_t)iv[s]*32 + 4*li);
    a0 = a1 = a2 = a3 = 0.f;
    #pragma unroll
    for (int s = 0; s < 8; ++s) {
        a0 += bflo(u[s].x); a1 += bfhi(u[s].x);
        a2 += bflo(u[s].y); a3 += bfhi(u[s].y);
    }
    if (deg > 64) {                 // essentially never (Poisson(16)); correctness fallback
        if (eg == 0) {
            for (int j = lo + 64; j < lo + deg; ++j) {
                int idx = src[j];
                uint2 uu = *(const uint2*)(Xb + (size_t)idx*32 + 4*li);
                a0 += bflo(uu.x); a1 += bfhi(uu.x);
                a2 += bflo(uu.y); a3 += bfhi(uu.y);
            }
        }
    }
    a0 += __shfl_xor(a0, 8);  a1 += __shfl_xor(a1, 8);
    a2 += __shfl_xor(a2, 8);  a3 += __shfl_xor(a3, 8);
    a0 += __shfl_xor(a0, 16); a1 += __shfl_xor(a1, 16);
    a2 += __shfl_xor(a2, 16); a3 += __shfl_xor(a3, 16);
    a0 += __shfl_xor(a0, 32); a1 += __shfl_xor(a1, 32);
    a2 += __shfl_xor(a2, 32); a3 += __shfl_xor(a3, 32);
}

// ---------- layer 1, group w: rb1_w = bf16(relu(Lap(Y0_w) + Zpre_w)) ----------
__global__ __launch_bounds__(256) void lap1g(
    const ushortT* __restrict__ Xb,   // Y0s + w*(N+1)*32
    const float*   __restrict__ P,
    int cown, int cz,                 // 32w, 96+32w
    const int* __restrict__ srcpT, const int* __restrict__ src,
    const int* __restrict__ row_ptr,
    ushortT* __restrict__ outw)       // rb1s + w*(N+1)*32
{
    int lane = threadIdx.x & 63;
    int t  = __builtin_amdgcn_readfirstlane((blockIdx.x << 2) + (threadIdx.x >> 6));
    int lo = __builtin_amdgcn_readfirstlane(row_ptr[t]);
    int deg = __builtin_amdgcn_readfirstlane(row_ptr[t+1]) - lo;
    int li = lane & 7;
    f4v xo = __builtin_nontemporal_load((const f4v*)(P + (size_t)t*PCOLS + cown) + li);
    f4v zz = __builtin_nontemporal_load((const f4v*)(P + (size_t)t*PCOLS + cz)   + li);
    float a0, a1, a2, a3;
    gather32(Xb, srcpT, src, t, lo, deg, lane, a0, a1, a2, a3);
    float inv = deg > 0 ? 1.f/(float)deg : 0.f;
    float mf  = deg > 0 ? 1.f : 0.f;
    if (lane < 8) {
        float o0 = fmaxf(mf*xo[0] - a0*inv + zz[0], 0.f);
        float o1 = fmaxf(mf*xo[1] - a1*inv + zz[1], 0.f);
        float o2 = fmaxf(mf*xo[2] - a2*inv + zz[2], 0.f);
        float o3 = fmaxf(mf*xo[3] - a3*inv + zz[3], 0.f);
        uint2 wr; wr.x = pack2(o0, o1); wr.y = pack2(o2, o3);
        *(uint2*)(outw + (size_t)t*32 + 4*li) = wr;
    }
}

// ---------- layers 2/3, group w: conv(HO) applied to Lap, then +Z, relu ----------
template<int HO>   // 32: out bf16 rb2_w ; 64: out fp32 ov (pre-mean)
__global__ __launch_bounds__(256) void lapcg(
    const ushortT* __restrict__ Xb,   // gather source, [N+1][32] for this group
    const float*   __restrict__ P,
    int cz,                           // 192+32w (HO=32) or 288+64w (HO=64)
    const float*   __restrict__ Wt,   // [HO][32] transposed weights for this group
    const int* __restrict__ srcpT, const int* __restrict__ src,
    const int* __restrict__ row_ptr,
    ushortT* __restrict__ outb,       // HO=32 path
    float*   __restrict__ ovw)        // HO=64 path (ov + 64w)
{
    int lane = threadIdx.x & 63;
    int j = (HO == 32) ? (lane & 31) : lane;
    float wv[32];
    {
        const float4* wp = (const float4*)(Wt + j*32);
        #pragma unroll
        for (int q8 = 0; q8 < 8; ++q8) {
            float4 v = wp[q8];
            wv[4*q8] = v.x; wv[4*q8+1] = v.y; wv[4*q8+2] = v.z; wv[4*q8+3] = v.w;
        }
    }
    int t  = __builtin_amdgcn_readfirstlane((blockIdx.x << 2) + (threadIdx.x >> 6));
    int lo = __builtin_amdgcn_readfirstlane(row_ptr[t]);
    int deg = __builtin_amdgcn_readfirstlane(row_ptr[t+1]) - lo;
    int li = lane & 7;
    uint2 ux = *(const uint2*)(Xb + (size_t)t*32 + 4*li);
    float z = __builtin_nontemporal_load(P + (size_t)t*PCOLS + cz + j);
    float a0, a1, a2, a3;
    gather32(Xb, srcpT, src, t, lo, deg, lane, a0, a1, a2, a3);
    float inv = deg > 0 ? 1.f/(float)deg : 0.f;
    float mf  = deg > 0 ? 1.f : 0.f;
    float lv[4];
    lv[0] = mf*bflo(ux.x) - a0*inv;
    lv[1] = mf*bfhi(ux.x) - a1*inv;
    lv[2] = mf*bflo(ux.y) - a2*inv;
    lv[3] = mf*bfhi(ux.y) - a3*inv;
    float acc = 0.f;
    #pragma unroll
    for (int f = 0; f < 32; ++f) {
        float in = rdlanef(lv[f & 3], f >> 2);   // feat f lives in lane f>>2, elem f&3
        acc = fmaf(in, wv[f], acc);
    }
    float o = fmaxf(acc + z, 0.f);
    if (HO == 32) {
        if (lane < 32) outb[(size_t)t*32 + j] = f2bfu(o);
    } else {
        __builtin_nontemporal_store(o, ovw + (size_t)t*192 + lane);
    }
}

// ---------- combine: out[t][f] = mean over width of ov[t][3f..3f+2] ----------
__global__ __launch_bounds__(256) void combine(const float* __restrict__ ov,
                                               float* __restrict__ out)
{
    int gid = blockIdx.x * 256 + threadIdx.x;
    int t = gid >> 6, f = gid & 63;
    const float* p = ov + (size_t)t*192 + 3*f;
    out[gid] = (p[0] + p[1] + p[2]) * (1.0f/3.0f);
}

extern "C" void kernel_launch(void* const* d_in, const int* in_sizes, int n_in,
                              void* d_out, int out_size, void* d_ws, size_t ws_size,
                              hipStream_t stream)
{
    const float* data    = (const float*)d_in[0];
    const int*   src     = (const int*)  d_in[1];
    const int*   tgt     = (const int*)  d_in[2];
    const float* W_pre   = (const float*)d_in[3];
    const float* b_pre   = (const float*)d_in[4];
    const float* T_pre   = (const float*)d_in[5];
    const float* bT_pre  = (const float*)d_in[6];
    const float* W_blk   = (const float*)d_in[7];
    const float* b_blk   = (const float*)d_in[8];   // cancels under Lap
    const float* T_blk   = (const float*)d_in[9];
    const float* bT_blk  = (const float*)d_in[10];
    const float* W_post  = (const float*)d_in[11];
    const float* b_post  = (const float*)d_in[12];  // cancels under Lap
    const float* T_post  = (const float*)d_in[13];
    const float* bT_post = (const float*)d_in[14];
    float* out = (float*)d_out;

    float* ws = (float*)d_ws;
    float*   P       = ws;                                   // N*512 f32
    float*   bcat    = P + (size_t)N_NODES * PCOLS;          // 512
    float*   Wt1     = bcat + 512;                           // 3072
    float*   Wt2     = Wt1 + 3072;                           // 6144
    float*   ov      = Wt2 + 6144;                           // N*192 f32 (aliases Ab: disjoint lifetime)
    int*     row_ptr = (int*)(ov + (size_t)N_NODES * 192);   // 50008
    int*     srcpT   = row_ptr + 50008;                      // N*64
    ushortT* Y0s     = (ushortT*)(srcpT + (size_t)N_NODES*64);  // 3*(N+1)*32 bf16
    ushortT* rb1s    = Y0s  + (size_t)3*(N_NODES+1)*32;
    ushortT* rb2s    = rb1s + (size_t)3*(N_NODES+1)*32;
    ushortT* Wb      = rb2s + (size_t)3*(N_NODES+1)*32;      // 512*128 bf16
    ushortT* Ab      = (ushortT*)ov;                          // N*128 bf16 (early lifetime)

    const size_t GSL = (size_t)(N_NODES+1)*32;   // group slice length

    pack_weights<<<(IN_F*PCOLS + 255)/256, 256, 0, stream>>>(
        W_pre, b_pre, T_pre, bT_pre, T_blk, bT_blk, T_post, bT_post,
        W_blk, W_post, Wb, bcat, Wt1, Wt2);

    convert_data<<<(N_NODES*IN_F/8 + 255)/256, 256, 0, stream>>>(data, Ab);

    build_row_ptr<<<(N_NODES + 1 + 255)/256, 256, 0, stream>>>(tgt, row_ptr, E_EDGES, N_NODES + 1);

    build_srcp<<<(N_NODES*64)/256, 256, 0, stream>>>(src, row_ptr, srcpT, Y0s, rb1s, rb2s);

    dim3 gg(PCOLS/128, (N_NODES + 127)/128);
    gemm_mfma<<<gg, 256, 0, stream>>>(Ab, Wb, bcat, P, Y0s, N_NODES);

    int lgrid = N_NODES / 4;   // wave per node
    // layer 1 (3 group passes; 3.2 MB gather slice per pass -> per-XCD L2 resident)
    for (int w = 0; w < 3; ++w)
        lap1g<<<lgrid, 256, 0, stream>>>(Y0s + w*GSL, P, 32*w, 96 + 32*w,
                                         srcpT, src, row_ptr, rb1s + w*GSL);
    // layer 2
    for (int w = 0; w < 3; ++w)
        lapcg<32><<<lgrid, 256, 0, stream>>>(rb1s + w*GSL, P, 192 + 32*w, Wt1 + w*1024,
                                             srcpT, src, row_ptr, rb2s + w*GSL, nullptr);
    // layer 3
    for (int w = 0; w < 3; ++w)
        lapcg<64><<<lgrid, 256, 0, stream>>>(rb2s + w*GSL, P, 288 + 64*w, Wt2 + w*2048,
                                             srcpT, src, row_ptr, nullptr, ov + 64*w);

    combine<<<(N_NODES*64)/256, 256, 0, stream>>>(ov, out);
}

// Round 10
// 320.573 us; speedup vs baseline: 1.8873x; 1.8873x over previous
//
#include <hip/hip_runtime.h>
#include <cstdint>
#include <cstddef>

#define N_NODES 50000
#define E_EDGES 800000
#define IN_F    128
#define PCOLS   512   // P: [0,96) Y0 | [96,192) Zpre | [192,288) Zblk | [288,480) Zpost | pad

typedef unsigned short ushortT;
typedef unsigned int   uintT;
typedef __attribute__((ext_vector_type(8))) short s8v;   // 8 bf16 (4 VGPR)
typedef __attribute__((ext_vector_type(4))) float f4v;   // 4 fp32 acc

__device__ __forceinline__ float bflo(uintT u){ union{uintT i;float f;}c; c.i=u<<16; return c.f; }
__device__ __forceinline__ float bfhi(uintT u){ union{uintT i;float f;}c; c.i=u&0xFFFF0000u; return c.f; }
__device__ __forceinline__ ushortT f2bfu(float f){
    union{float f;uintT u;}c; c.f=f;
    uintT r = c.u + 0x7FFF + ((c.u>>16)&1);
    return (ushortT)(r>>16);
}
__device__ __forceinline__ uintT pack2(float a, float b){
    return (uintT)f2bfu(a) | ((uintT)f2bfu(b) << 16);
}
__device__ __forceinline__ float rdlanef(float v, int sl){
    return __int_as_float(__builtin_amdgcn_readlane(__float_as_int(v), sl));
}

// ---------- pack weights: Wb [512][128] bf16, bcat[512] fp32, Wp2 [3][16][64] float2 ----------
__global__ void pack_weights(const float* __restrict__ Wp,  const float* __restrict__ bp,
                             const float* __restrict__ Tp,  const float* __restrict__ bTp,
                             const float* __restrict__ Tb,  const float* __restrict__ bTb,
                             const float* __restrict__ Tpo, const float* __restrict__ bTpo,
                             const float* __restrict__ Wpost,
                             ushortT* __restrict__ Wb, float* __restrict__ bcat,
                             float2* __restrict__ Wp2)
{
    int id = blockIdx.x * 256 + threadIdx.x;
    if (id >= IN_F * PCOLS) return;
    int k = id >> 9;
    int c = id & 511;
    float v;
    if      (c < 96)  v = Wp [k*96  + c];
    else if (c < 192) v = Tp [k*96  + (c-96)];
    else if (c < 288) v = Tb [k*96  + (c-192)];
    else if (c < 480) v = Tpo[k*192 + (c-288)];
    else              v = 0.f;
    Wb[(size_t)c*IN_F + k] = f2bfu(v);
    if (k == 0) {
        float b;
        if      (c < 96)  b = bp  [c];
        else if (c < 192) b = bTp [c-96];
        else if (c < 288) b = bTb [c-192];
        else if (c < 480) b = bTpo[c-288];
        else              b = 0.f;
        bcat[c] = b;
    }
    if (id < 3*16*64) {   // Wp2[(w*16+i2)*64+j] = (Wpost[w][2i2][j], Wpost[w][2i2+1][j])
        int w = id >> 10, r = id & 1023;
        int i2 = r >> 6, j = r & 63;
        Wp2[id] = make_float2(Wpost[(w*32 + 2*i2)*64 + j],
                              Wpost[(w*32 + 2*i2 + 1)*64 + j]);
    }
}

// ---------- convert data fp32 -> Ab bf16 [N][128] ----------
__global__ void convert_data(const float* __restrict__ A, ushortT* __restrict__ Ab)
{
    int gid = blockIdx.x * 256 + threadIdx.x;
    size_t off = (size_t)gid * 8;
    float4 v0 = *(const float4*)(A + off);
    float4 v1 = *(const float4*)(A + off + 4);
    uint4 u;
    u.x = pack2(v0.x, v0.y); u.y = pack2(v0.z, v0.w);
    u.z = pack2(v1.x, v1.y); u.w = pack2(v1.z, v1.w);
    *(uint4*)(Ab + off) = u;
}

// ---------- row_ptr via binary search on sorted tgt ----------
__global__ void build_row_ptr(const int* __restrict__ tgt, int* __restrict__ row_ptr,
                              int E, int Np1)
{
    int t = blockIdx.x * 256 + threadIdx.x;
    if (t >= Np1) return;
    int lo = 0, hi = E;
    while (lo < hi) {
        int mid = (lo + hi) >> 1;
        if (tgt[mid] < t) lo = mid + 1; else hi = mid;
    }
    row_ptr[t] = lo;
}

// ---------- srcp[t][slot] = slot<deg ? src[lo+slot] : N ; zero rows of gather sources ----------
__global__ void build_srcp(const int* __restrict__ src, const int* __restrict__ row_ptr,
                           int* __restrict__ srcp,
                           ushortT* __restrict__ Y0b, ushortT* __restrict__ rb1,
                           ushortT* __restrict__ rb2)
{
    int gid = blockIdx.x * 256 + threadIdx.x;   // N*64 threads
    int t = gid >> 6, slot = gid & 63;
    int lo = row_ptr[t];
    int deg = row_ptr[t+1] - lo;
    srcp[gid] = slot < deg ? src[lo + slot] : N_NODES;
    if (gid < 96) {
        Y0b[(size_t)N_NODES*96 + gid] = 0;
        rb1[(size_t)N_NODES*96 + gid] = 0;
        rb2[(size_t)N_NODES*96 + gid] = 0;
    }
}

// ---------- MFMA GEMM: P[M,512] = Ab[M,128] @ Wb^T + bcat ; also emit Y0b bf16 ----------
__global__ __launch_bounds__(256, 2) void gemm_mfma(const ushortT* __restrict__ Ab,
                                                    const ushortT* __restrict__ Wb,
                                                    const float* __restrict__ bcat,
                                                    float* __restrict__ P,
                                                    ushortT* __restrict__ Y0b, int M)
{
    __shared__ ushortT Asl[128][72];
    __shared__ ushortT Bsl[128][72];
    int tid = threadIdx.x;
    int nb = blockIdx.x * 128;
    int mb = blockIdx.y * 128;
    int wv = tid >> 6, lane = tid & 63;
    int wm = wv >> 1, wn = wv & 1;
    int cl = lane & 15, q = lane >> 4;

    f4v acc[4][4];
    #pragma unroll
    for (int i = 0; i < 4; ++i)
        #pragma unroll
        for (int j = 0; j < 4; ++j) acc[i][j] = (f4v)0.f;

    for (int kt = 0; kt < IN_F; kt += 64) {
        if (kt) __syncthreads();
        #pragma unroll
        for (int r = 0; r < 4; ++r) {
            int idx = tid + 256*r;
            int row = idx >> 3, qq = idx & 7;
            int gm = mb + row;
            uint4 v = make_uint4(0,0,0,0);
            if (gm < M) v = *(const uint4*)(Ab + (size_t)gm*IN_F + kt + qq*8);
            *(uint4*)(&Asl[row][qq*8]) = v;
        }
        #pragma unroll
        for (int r = 0; r < 4; ++r) {
            int idx = tid + 256*r;
            int row = idx >> 3, qq = idx & 7;
            uint4 v = *(const uint4*)(Wb + (size_t)(nb+row)*IN_F + kt + qq*8);
            *(uint4*)(&Bsl[row][qq*8]) = v;
        }
        __syncthreads();
        #pragma unroll
        for (int ks = 0; ks < 2; ++ks) {
            int ko = ks*32 + q*8;
            s8v af[4], bf[4];
            #pragma unroll
            for (int mt = 0; mt < 4; ++mt)
                af[mt] = *(const s8v*)(&Asl[wm*64 + mt*16 + cl][ko]);
            #pragma unroll
            for (int nt = 0; nt < 4; ++nt)
                bf[nt] = *(const s8v*)(&Bsl[wn*64 + nt*16 + cl][ko]);
            #pragma unroll
            for (int mt = 0; mt < 4; ++mt)
                #pragma unroll
                for (int nt = 0; nt < 4; ++nt)
                    acc[mt][nt] = __builtin_amdgcn_mfma_f32_16x16x32_bf16(af[mt], bf[nt], acc[mt][nt], 0, 0, 0);
        }
    }

    bool y0blk = (nb == 0) && (wn == 0);
    #pragma unroll
    for (int nt = 0; nt < 4; ++nt) {
        int gn = nb + wn*64 + nt*16 + cl;
        float bv = bcat[gn];
        bool doY = y0blk && (gn < 96);
        #pragma unroll
        for (int mt = 0; mt < 4; ++mt) {
            int gm0 = mb + wm*64 + mt*16 + q*4;
            #pragma unroll
            for (int r = 0; r < 4; ++r) {
                int gm = gm0 + r;
                if (gm < M) {
                    float val = acc[mt][nt][r] + bv;
                    P[(size_t)gm*PCOLS + gn] = val;
                    if (doY) Y0b[(size_t)gm*96 + gn] = f2bfu(val);
                }
            }
        }
    }
}

// ===== gather core: 32-deep single window (covers deg<=32 in ONE round trip) =====
#define GATHER96(Xb, lo, deg, sv, pL, sx, sy)                                     \
    float sx, sy;                                                                 \
    {                                                                             \
        float c0x=0.f,c0y=0.f,c1x=0.f,c1y=0.f,c2x=0.f,c2y=0.f,c3x=0.f,c3y=0.f;    \
        float c4x=0.f,c4y=0.f,c5x=0.f,c5y=0.f,c6x=0.f,c6y=0.f,c7x=0.f,c7y=0.f;    \
        int dmax = deg < 64 ? deg : 64;                                           \
        _Pragma("unroll 1")                                                       \
        for (int w_ = 0; w_ < dmax; w_ += 32) {                                   \
            uintT u[32];                                                          \
            _Pragma("unroll")                                                     \
            for (int kk = 0; kk < 32; ++kk) {                                     \
                int idx = __builtin_amdgcn_readlane(sv, w_ + kk);                 \
                u[kk] = *(const uintT*)(Xb + (size_t)idx*96 + 2*pL);              \
            }                                                                     \
            _Pragma("unroll")                                                     \
            for (int kk = 0; kk < 32; ++kk) {                                     \
                float lo_ = bflo(u[kk]), hi_ = bfhi(u[kk]);                       \
                switch (kk & 7) {                                                 \
                    case 0: c0x += lo_; c0y += hi_; break;                        \
                    case 1: c1x += lo_; c1y += hi_; break;                        \
                    case 2: c2x += lo_; c2y += hi_; break;                        \
                    case 3: c3x += lo_; c3y += hi_; break;                        \
                    case 4: c4x += lo_; c4y += hi_; break;                        \
                    case 5: c5x += lo_; c5y += hi_; break;                        \
                    case 6: c6x += lo_; c6y += hi_; break;                        \
                    default:c7x += lo_; c7y += hi_; break;                        \
                }                                                                 \
            }                                                                     \
        }                                                                         \
        if (deg > 64) {                                                           \
            _Pragma("unroll 1")                                                   \
            for (int j_ = lo + 64; j_ < lo + deg; ++j_) {                         \
                int idx = src[j_];                                                \
                uintT u0 = *(const uintT*)(Xb + (size_t)idx*96 + 2*pL);           \
                c0x += bflo(u0); c0y += bfhi(u0);                                 \
            }                                                                     \
        }                                                                         \
        sx = ((c0x+c1x)+(c2x+c3x)) + ((c4x+c5x)+(c6x+c7x));                       \
        sy = ((c0y+c1y)+(c2y+c3y)) + ((c4y+c5y)+(c6y+c7y));                       \
    }

// ---------- layer 1: rb1 = bf16(relu(Lap(Y0) + Zpre)), wave per node ----------
__global__ __launch_bounds__(256) void lap1(
    const ushortT* __restrict__ Xb,    // Y0b [N+1,96]
    const float*   __restrict__ Pown,  // P (cols 0..95 fp32 own-x)
    const float*   __restrict__ Z,     // P + 96
    const int* __restrict__ srcp, const int* __restrict__ src,
    const int* __restrict__ row_ptr,
    ushortT* __restrict__ rb1)
{
    int lane = threadIdx.x & 63;
    int t  = __builtin_amdgcn_readfirstlane((blockIdx.x << 2) + (threadIdx.x >> 6));
    int lo = __builtin_amdgcn_readfirstlane(row_ptr[t]);
    int deg = __builtin_amdgcn_readfirstlane(row_ptr[t+1]) - lo;
    int pL = lane < 48 ? lane : 0;
    int sv = srcp[t*64 + lane];
    float2 xr = *(const float2*)(Pown + (size_t)t*PCOLS + 2*pL);
    float2 zr = *(const float2*)(Z    + (size_t)t*PCOLS + 2*pL);

    GATHER96(Xb, lo, deg, sv, pL, sx, sy)

    float inv = deg > 0 ? 1.f/(float)deg : 0.f;
    float mf  = deg > 0 ? 1.f : 0.f;
    if (lane < 48) {
        float ox = fmaxf(mf*xr.x - sx*inv + zr.x, 0.f);
        float oy = fmaxf(mf*xr.y - sy*inv + zr.y, 0.f);
        *(uintT*)(rb1 + (size_t)t*96 + 2*pL) = pack2(ox, oy);
    }
}

// ---------- layer 2: rb2 = bf16(relu(Lap(rb1)@W_blk + Zblk))  [conv commuted past Lap] ----------
#define CPB 20
__global__ __launch_bounds__(256) void lap2(
    const ushortT* __restrict__ Xb,    // rb1 [N+1,96]
    const float*   __restrict__ Z,     // P + 192 (Zblk)
    const int* __restrict__ srcp, const int* __restrict__ src,
    const int* __restrict__ row_ptr,
    const float* __restrict__ Wblk,    // [3][32][32] flat
    ushortT* __restrict__ rb2)
{
    __shared__ float wS[3*32*32];
    for (int i = threadIdx.x; i < 3072; i += 256) wS[i] = Wblk[i];
    __syncthreads();

    int lane = threadIdx.x & 63;
    int wvw  = threadIdx.x >> 6;
    int pL = lane < 48 ? lane : 0;
    int w  = pL >> 4;            // group (uniform per 16-lane slab)
    int jj = pL & 15;            // out pair index within group
    const float2* wc = ((const float2*)wS) + (w*512 + jj);   // &W[w][0][2jj]

    int svn = srcp[(blockIdx.x*CPB + wvw)*64 + lane];   // prefetch trip 0
    #pragma unroll 1
    for (int trip = 0; trip < CPB/4; ++trip) {
        int t  = __builtin_amdgcn_readfirstlane(blockIdx.x*CPB + 4*trip + wvw);
        int lo = __builtin_amdgcn_readfirstlane(row_ptr[t]);
        int deg = __builtin_amdgcn_readfirstlane(row_ptr[t+1]) - lo;
        int sv = svn;
        if (trip + 1 < CPB/4) svn = srcp[(t+4)*64 + lane];   // prefetch next trip
        uintT ux = *(const uintT*)(Xb + (size_t)t*96 + 2*pL);
        float2 zr = *(const float2*)(Z + (size_t)t*PCOLS + 2*pL);

        GATHER96(Xb, lo, deg, sv, pL, sx, sy)

        float inv = deg > 0 ? 1.f/(float)deg : 0.f;
        float mf  = deg > 0 ? 1.f : 0.f;
        float Lx = mf*bflo(ux) - sx*inv;    // Lap feat 2pL
        float Ly = mf*bfhi(ux) - sy*inv;    // Lap feat 2pL+1

        // conv (no bias): out channels (2pL, 2pL+1), inputs = group-w feats via shfl
        float accx = 0.f, accy = 0.f;
        #pragma unroll
        for (int d = 0; d < 16; ++d) {
            int sl = w*16 + d;
            float ax = __shfl(Lx, sl);      // feat 32w+2d
            float ay = __shfl(Ly, sl);      // feat 32w+2d+1
            float2 wa = wc[(2*d)*16];       // W[w][2d][2jj..2jj+1]
            float2 wb = wc[(2*d+1)*16];
            accx = fmaf(ax, wa.x, accx); accx = fmaf(ay, wb.x, accx);
            accy = fmaf(ax, wa.y, accy); accy = fmaf(ay, wb.y, accy);
        }
        if (lane < 48) {
            float ox = fmaxf(accx + zr.x, 0.f);
            float oy = fmaxf(accy + zr.y, 0.f);
            *(uintT*)(rb2 + (size_t)t*96 + 2*pL) = pack2(ox, oy);
        }
    }
}

// ---------- layer 3: out = widthmean(relu(Lap(rb2)@W_post + Zpost)) ----------
__global__ __launch_bounds__(256) void lap3(
    const ushortT* __restrict__ Xb,    // rb2 [N+1,96]
    const float*   __restrict__ Z,     // P + 288 (Zpost)
    const int* __restrict__ srcp, const int* __restrict__ src,
    const int* __restrict__ row_ptr,
    const float2* __restrict__ Wp2,    // [3][16][64] float2
    float* __restrict__ out)
{
    __shared__ float2 wS[3*16*64];
    for (int i = threadIdx.x; i < 3072; i += 256) wS[i] = Wp2[i];
    __syncthreads();

    int lane = threadIdx.x & 63;
    int wvw  = threadIdx.x >> 6;
    int pL = lane < 48 ? lane : 0;
    const float2* wl = wS + lane;      // step 64 float2 per (w,i2)

    int svn = srcp[(blockIdx.x*CPB + wvw)*64 + lane];   // prefetch trip 0
    #pragma unroll 1
    for (int trip = 0; trip < CPB/4; ++trip) {
        int t  = __builtin_amdgcn_readfirstlane(blockIdx.x*CPB + 4*trip + wvw);
        int lo = __builtin_amdgcn_readfirstlane(row_ptr[t]);
        int deg = __builtin_amdgcn_readfirstlane(row_ptr[t+1]) - lo;
        int sv = svn;
        if (trip + 1 < CPB/4) svn = srcp[(t+4)*64 + lane];   // prefetch next trip
        uintT ux = *(const uintT*)(Xb + (size_t)t*96 + 2*pL);
        float z0 = Z[(size_t)t*PCOLS + lane];
        float z1 = Z[(size_t)t*PCOLS + 64 + lane];
        float z2 = Z[(size_t)t*PCOLS + 128 + lane];

        GATHER96(Xb, lo, deg, sv, pL, sx, sy)

        float inv = deg > 0 ? 1.f/(float)deg : 0.f;
        float mf  = deg > 0 ? 1.f : 0.f;
        float Lx = mf*bflo(ux) - sx*inv;
        float Ly = mf*bfhi(ux) - sy*inv;

        // conv: lane computes channels {L, 64+L, 128+L}; acts broadcast via readlane
        float a0 = 0.f, a1 = 0.f, a2 = 0.f;
        #pragma unroll
        for (int w2 = 0; w2 < 3; ++w2) {
            float acc = 0.f;
            #pragma unroll
            for (int i2 = 0; i2 < 16; ++i2) {
                float ax = rdlanef(Lx, 16*w2 + i2);   // feat 32w2+2i2
                float ay = rdlanef(Ly, 16*w2 + i2);   // feat 32w2+2i2+1
                float2 p = wl[(w2*16 + i2)*64];
                acc = fmaf(ax, p.x, acc);
                acc = fmaf(ay, p.y, acc);
            }
            if (w2 == 0) a0 = acc; else if (w2 == 1) a1 = acc; else a2 = acc;
        }
        float o0 = fmaxf(a0 + z0, 0.f);   // channel lane
        float o1 = fmaxf(a1 + z1, 0.f);   // channel 64+lane
        float o2 = fmaxf(a2 + z2, 0.f);   // channel 128+lane
        // width-mean: final[f] = (v(3f)+v(3f+1)+v(3f+2))/3, v(c) = o_{c>>6} @ lane c&63
        float r = 0.f;
        #pragma unroll
        for (int q = 0; q < 3; ++q) {
            int c = 3*lane + q;
            int sl = c & 63, wsel = c >> 6;
            float v0 = __shfl(o0, sl);
            float v1 = __shfl(o1, sl);
            float v2 = __shfl(o2, sl);
            r += (wsel == 0) ? v0 : ((wsel == 1) ? v1 : v2);
        }
        out[(size_t)t*64 + lane] = r * (1.0f/3.0f);
    }
}

extern "C" void kernel_launch(void* const* d_in, const int* in_sizes, int n_in,
                              void* d_out, int out_size, void* d_ws, size_t ws_size,
                              hipStream_t stream)
{
    const float* data    = (const float*)d_in[0];
    const int*   src     = (const int*)  d_in[1];
    const int*   tgt     = (const int*)  d_in[2];
    const float* W_pre   = (const float*)d_in[3];
    const float* b_pre   = (const float*)d_in[4];
    const float* T_pre   = (const float*)d_in[5];
    const float* bT_pre  = (const float*)d_in[6];
    const float* W_blk   = (const float*)d_in[7];
    const float* b_blk   = (const float*)d_in[8];   // cancels in Lap — unused
    const float* T_blk   = (const float*)d_in[9];
    const float* bT_blk  = (const float*)d_in[10];
    const float* W_post  = (const float*)d_in[11];
    const float* b_post  = (const float*)d_in[12];  // cancels in Lap — unused
    const float* T_post  = (const float*)d_in[13];
    const float* bT_post = (const float*)d_in[14];
    float* out = (float*)d_out;

    float* ws = (float*)d_ws;
    float*   P       = ws;                                   // N*512 f32
    float*   bcat    = P + (size_t)N_NODES * PCOLS;          // 512
    float2*  Wp2     = (float2*)(bcat + 512);                // 3*16*64 float2
    int*     row_ptr = (int*)(Wp2 + 3*16*64);                // 50008
    int*     srcp    = row_ptr + 50008;                      // N*64
    ushortT* Y0b     = (ushortT*)(srcp + (size_t)N_NODES*64);   // (N+1)*96 bf16
    ushortT* rb1     = Y0b + (size_t)(N_NODES+1) * 96;          // (N+1)*96 bf16
    ushortT* rb2     = rb1 + (size_t)(N_NODES+1) * 96;          // (N+1)*96 bf16
    ushortT* Ab      = rb2 + (size_t)(N_NODES+1) * 96;          // N*128 bf16
    ushortT* Wb      = Ab  + (size_t)N_NODES * IN_F;            // 512*128 bf16

    pack_weights<<<(IN_F*PCOLS + 255)/256, 256, 0, stream>>>(
        W_pre, b_pre, T_pre, bT_pre, T_blk, bT_blk, T_post, bT_post,
        W_post, Wb, bcat, Wp2);

    convert_data<<<(N_NODES*IN_F/8 + 255)/256, 256, 0, stream>>>(data, Ab);

    build_row_ptr<<<(N_NODES + 1 + 255)/256, 256, 0, stream>>>(tgt, row_ptr, E_EDGES, N_NODES + 1);

    build_srcp<<<(N_NODES*64)/256, 256, 0, stream>>>(src, row_ptr, srcp, Y0b, rb1, rb2);

    dim3 gg(PCOLS/128, (N_NODES + 127)/128);
    gemm_mfma<<<gg, 256, 0, stream>>>(Ab, Wb, bcat, P, Y0b, N_NODES);

    lap1<<<(N_NODES + 3)/4, 256, 0, stream>>>(Y0b, P, P + 96, srcp, src, row_ptr, rb1);
    lap2<<<N_NODES/CPB, 256, 0, stream>>>(rb1, P + 192, srcp, src, row_ptr, W_blk, rb2);
    lap3<<<N_NODES/CPB, 256, 0, stream>>>(rb2, P + 288, srcp, src, row_ptr, Wp2, out);
}

// Round 11
// 304.103 us; speedup vs baseline: 1.9896x; 1.0542x over previous
//
#include <hip/hip_runtime.h>
#include <cstdint>
#include <cstddef>

#define N_NODES 50000
#define E_EDGES 800000
#define IN_F    128
#define PCOLS   512   // P: [0,96) Y0 | [96,192) Zpre | [192,288) Zblk | [288,480) Zpost | pad

typedef unsigned short ushortT;
typedef unsigned int   uintT;
typedef __attribute__((ext_vector_type(8))) short s8v;   // 8 bf16 (4 VGPR)
typedef __attribute__((ext_vector_type(4))) float f4v;   // 4 fp32 acc

__device__ __forceinline__ float bflo(uintT u){ union{uintT i;float f;}c; c.i=u<<16; return c.f; }
__device__ __forceinline__ float bfhi(uintT u){ union{uintT i;float f;}c; c.i=u&0xFFFF0000u; return c.f; }
__device__ __forceinline__ ushortT f2bfu(float f){
    union{float f;uintT u;}c; c.f=f;
    uintT r = c.u + 0x7FFF + ((c.u>>16)&1);
    return (ushortT)(r>>16);
}
__device__ __forceinline__ uintT pack2(float a, float b){
    return (uintT)f2bfu(a) | ((uintT)f2bfu(b) << 16);
}
__device__ __forceinline__ float rdlanef(float v, int sl){
    return __int_as_float(__builtin_amdgcn_readlane(__float_as_int(v), sl));
}

// ---------- prep1: pack weights + convert data + row_ptr (all independent) ----------
// grid = 800000 threads exactly (N*IN_F/8)
__global__ void prep1(const float* __restrict__ A,
                      const float* __restrict__ Wp,  const float* __restrict__ bp,
                      const float* __restrict__ Tp,  const float* __restrict__ bTp,
                      const float* __restrict__ Tb,  const float* __restrict__ bTb,
                      const float* __restrict__ Tpo, const float* __restrict__ bTpo,
                      const float* __restrict__ Wpost,
                      const int* __restrict__ tgt,
                      ushortT* __restrict__ Wb, float* __restrict__ bcat,
                      float2* __restrict__ Wp2,
                      ushortT* __restrict__ Ab, int* __restrict__ row_ptr)
{
    int gid = blockIdx.x * 256 + threadIdx.x;
    // convert data fp32 -> bf16, 8 elems/thread (covers all 800000 threads)
    {
        size_t off = (size_t)gid * 8;
        float4 v0 = *(const float4*)(A + off);
        float4 v1 = *(const float4*)(A + off + 4);
        uint4 u;
        u.x = pack2(v0.x, v0.y); u.y = pack2(v0.z, v0.w);
        u.z = pack2(v1.x, v1.y); u.w = pack2(v1.z, v1.w);
        *(uint4*)(Ab + off) = u;
    }
    // pack weights
    if (gid < IN_F * PCOLS) {
        int k = gid >> 9;
        int c = gid & 511;
        float v;
        if      (c < 96)  v = Wp [k*96  + c];
        else if (c < 192) v = Tp [k*96  + (c-96)];
        else if (c < 288) v = Tb [k*96  + (c-192)];
        else if (c < 480) v = Tpo[k*192 + (c-288)];
        else              v = 0.f;
        Wb[(size_t)c*IN_F + k] = f2bfu(v);
        if (k == 0) {
            float b;
            if      (c < 96)  b = bp  [c];
            else if (c < 192) b = bTp [c-96];
            else if (c < 288) b = bTb [c-192];
            else if (c < 480) b = bTpo[c-288];
            else              b = 0.f;
            bcat[c] = b;
        }
        if (gid < 3*16*64) {   // Wp2[(w*16+i2)*64+j] = (Wpost[w][2i2][j], Wpost[w][2i2+1][j])
            int w = gid >> 10, r = gid & 1023;
            int i2 = r >> 6, j = r & 63;
            Wp2[gid] = make_float2(Wpost[(w*32 + 2*i2)*64 + j],
                                   Wpost[(w*32 + 2*i2 + 1)*64 + j]);
        }
    }
    // row_ptr via binary search on sorted tgt
    if (gid <= N_NODES) {
        int lo = 0, hi = E_EDGES;
        while (lo < hi) {
            int mid = (lo + hi) >> 1;
            if (tgt[mid] < gid) lo = mid + 1; else hi = mid;
        }
        row_ptr[gid] = lo;
    }
}

// ---------- srcp[t][slot] = slot<deg ? src[lo+slot] : N ; zero rows of gather sources ----------
__global__ void build_srcp(const int* __restrict__ src, const int* __restrict__ row_ptr,
                           int* __restrict__ srcp,
                           ushortT* __restrict__ Y0b, ushortT* __restrict__ rb1,
                           ushortT* __restrict__ rb2)
{
    int gid = blockIdx.x * 256 + threadIdx.x;   // N*64 threads
    int t = gid >> 6, slot = gid & 63;
    int lo = row_ptr[t];
    int deg = row_ptr[t+1] - lo;
    srcp[gid] = slot < deg ? src[lo + slot] : N_NODES;
    if (gid < 96) {
        Y0b[(size_t)N_NODES*96 + gid] = 0;
        rb1[(size_t)N_NODES*96 + gid] = 0;
        rb2[(size_t)N_NODES*96 + gid] = 0;
    }
}

// ---------- MFMA GEMM: P[M,512] = Ab[M,128] @ Wb^T + bcat ; also emit Y0b bf16 ----------
__global__ __launch_bounds__(256, 2) void gemm_mfma(const ushortT* __restrict__ Ab,
                                                    const ushortT* __restrict__ Wb,
                                                    const float* __restrict__ bcat,
                                                    float* __restrict__ P,
                                                    ushortT* __restrict__ Y0b, int M)
{
    __shared__ ushortT Asl[128][72];
    __shared__ ushortT Bsl[128][72];
    int tid = threadIdx.x;
    int nb = blockIdx.x * 128;
    int mb = blockIdx.y * 128;
    int wv = tid >> 6, lane = tid & 63;
    int wm = wv >> 1, wn = wv & 1;
    int cl = lane & 15, q = lane >> 4;

    f4v acc[4][4];
    #pragma unroll
    for (int i = 0; i < 4; ++i)
        #pragma unroll
        for (int j = 0; j < 4; ++j) acc[i][j] = (f4v)0.f;

    for (int kt = 0; kt < IN_F; kt += 64) {
        if (kt) __syncthreads();
        #pragma unroll
        for (int r = 0; r < 4; ++r) {
            int idx = tid + 256*r;
            int row = idx >> 3, qq = idx & 7;
            int gm = mb + row;
            uint4 v = make_uint4(0,0,0,0);
            if (gm < M) v = *(const uint4*)(Ab + (size_t)gm*IN_F + kt + qq*8);
            *(uint4*)(&Asl[row][qq*8]) = v;
        }
        #pragma unroll
        for (int r = 0; r < 4; ++r) {
            int idx = tid + 256*r;
            int row = idx >> 3, qq = idx & 7;
            uint4 v = *(const uint4*)(Wb + (size_t)(nb+row)*IN_F + kt + qq*8);
            *(uint4*)(&Bsl[row][qq*8]) = v;
        }
        __syncthreads();
        #pragma unroll
        for (int ks = 0; ks < 2; ++ks) {
            int ko = ks*32 + q*8;
            s8v af[4], bf[4];
            #pragma unroll
            for (int mt = 0; mt < 4; ++mt)
                af[mt] = *(const s8v*)(&Asl[wm*64 + mt*16 + cl][ko]);
            #pragma unroll
            for (int nt = 0; nt < 4; ++nt)
                bf[nt] = *(const s8v*)(&Bsl[wn*64 + nt*16 + cl][ko]);
            #pragma unroll
            for (int mt = 0; mt < 4; ++mt)
                #pragma unroll
                for (int nt = 0; nt < 4; ++nt)
                    acc[mt][nt] = __builtin_amdgcn_mfma_f32_16x16x32_bf16(af[mt], bf[nt], acc[mt][nt], 0, 0, 0);
        }
    }

    bool y0blk = (nb == 0) && (wn == 0);
    #pragma unroll
    for (int nt = 0; nt < 4; ++nt) {
        int gn = nb + wn*64 + nt*16 + cl;
        float bv = bcat[gn];
        bool doY = y0blk && (gn < 96);
        #pragma unroll
        for (int mt = 0; mt < 4; ++mt) {
            int gm0 = mb + wm*64 + mt*16 + q*4;
            #pragma unroll
            for (int r = 0; r < 4; ++r) {
                int gm = gm0 + r;
                if (gm < M) {
                    float val = acc[mt][nt][r] + bv;
                    P[(size_t)gm*PCOLS + gn] = val;
                    if (doY) Y0b[(size_t)gm*96 + gn] = f2bfu(val);
                }
            }
        }
    }
}

// ===== shared gather core (R7-proven): 16-deep windows over 96-bf16 rows =====
#define GATHER96(Xb, lo, deg, sv, pL, sx, sy)                                     \
    float sx, sy;                                                                 \
    {                                                                             \
        float c0x=0.f,c0y=0.f,c1x=0.f,c1y=0.f,c2x=0.f,c2y=0.f,c3x=0.f,c3y=0.f;    \
        int dmax = deg < 64 ? deg : 64;                                           \
        _Pragma("unroll 1")                                                       \
        for (int w_ = 0; w_ < dmax; w_ += 16) {                                   \
            uintT u[16];                                                          \
            _Pragma("unroll")                                                     \
            for (int kk = 0; kk < 16; ++kk) {                                     \
                int idx = __builtin_amdgcn_readlane(sv, w_ + kk);                 \
                u[kk] = *(const uintT*)(Xb + (size_t)idx*96 + 2*pL);              \
            }                                                                     \
            _Pragma("unroll")                                                     \
            for (int kk = 0; kk < 16; ++kk) {                                     \
                float lo_ = bflo(u[kk]), hi_ = bfhi(u[kk]);                       \
                switch (kk & 3) {                                                 \
                    case 0: c0x += lo_; c0y += hi_; break;                        \
                    case 1: c1x += lo_; c1y += hi_; break;                        \
                    case 2: c2x += lo_; c2y += hi_; break;                        \
                    default:c3x += lo_; c3y += hi_; break;                        \
                }                                                                 \
            }                                                                     \
        }                                                                         \
        if (deg > 64) {                                                           \
            _Pragma("unroll 1")                                                   \
            for (int j_ = lo + 64; j_ < lo + deg; ++j_) {                         \
                int idx = src[j_];                                                \
                uintT u0 = *(const uintT*)(Xb + (size_t)idx*96 + 2*pL);           \
                c0x += bflo(u0); c0y += bfhi(u0);                                 \
            }                                                                     \
        }                                                                         \
        sx = (c0x+c1x)+(c2x+c3x);                                                 \
        sy = (c0y+c1y)+(c2y+c3y);                                                 \
    }

// ---------- layer 1: rb1 = bf16(relu(Lap(Y0) + Zpre)), wave per node ----------
__global__ __launch_bounds__(256) void lap1(
    const ushortT* __restrict__ Xb,    // Y0b [N+1,96]
    const float*   __restrict__ Pown,  // P (cols 0..95 fp32 own-x)
    const float*   __restrict__ Z,     // P + 96
    const int* __restrict__ srcp, const int* __restrict__ src,
    const int* __restrict__ row_ptr,
    ushortT* __restrict__ rb1)
{
    int lane = threadIdx.x & 63;
    int t  = __builtin_amdgcn_readfirstlane((blockIdx.x << 2) + (threadIdx.x >> 6));
    int lo = __builtin_amdgcn_readfirstlane(row_ptr[t]);
    int deg = __builtin_amdgcn_readfirstlane(row_ptr[t+1]) - lo;
    int pL = lane < 48 ? lane : 0;
    int sv = srcp[t*64 + lane];
    float2 xr = *(const float2*)(Pown + (size_t)t*PCOLS + 2*pL);
    float2 zr = *(const float2*)(Z    + (size_t)t*PCOLS + 2*pL);

    GATHER96(Xb, lo, deg, sv, pL, sx, sy)

    float inv = deg > 0 ? 1.f/(float)deg : 0.f;
    float mf  = deg > 0 ? 1.f : 0.f;
    if (lane < 48) {
        float ox = fmaxf(mf*xr.x - sx*inv + zr.x, 0.f);
        float oy = fmaxf(mf*xr.y - sy*inv + zr.y, 0.f);
        *(uintT*)(rb1 + (size_t)t*96 + 2*pL) = pack2(ox, oy);
    }
}

// ---------- layer 2: rb2 = bf16(relu(Lap(rb1)@W_blk + Zblk)), wave per node ----------
__global__ __launch_bounds__(256) void lap2(
    const ushortT* __restrict__ Xb,    // rb1 [N+1,96]
    const float*   __restrict__ Z,     // P + 192 (Zblk)
    const int* __restrict__ srcp, const int* __restrict__ src,
    const int* __restrict__ row_ptr,
    const float* __restrict__ Wblk,    // [3][32][32] flat
    ushortT* __restrict__ rb2)
{
    __shared__ float wS[3*32*32];
    int lane = threadIdx.x & 63;
    int t  = __builtin_amdgcn_readfirstlane((blockIdx.x << 2) + (threadIdx.x >> 6));
    int pL = lane < 48 ? lane : 0;
    // issue node-local loads first; weight staging below hides their latency
    int sv = srcp[t*64 + lane];
    int lo = __builtin_amdgcn_readfirstlane(row_ptr[t]);
    int deg = __builtin_amdgcn_readfirstlane(row_ptr[t+1]) - lo;
    uintT ux = *(const uintT*)(Xb + (size_t)t*96 + 2*pL);
    float2 zr = *(const float2*)(Z + (size_t)t*PCOLS + 2*pL);

    for (int i = threadIdx.x; i < 3072; i += 256) wS[i] = Wblk[i];
    __syncthreads();

    int w  = pL >> 4;            // group (uniform per 16-lane slab)
    int jj = pL & 15;            // out pair index within group
    const float2* wc = ((const float2*)wS) + (w*512 + jj);   // &W[w][0][2jj]

    GATHER96(Xb, lo, deg, sv, pL, sx, sy)

    float inv = deg > 0 ? 1.f/(float)deg : 0.f;
    float mf  = deg > 0 ? 1.f : 0.f;
    float Lx = mf*bflo(ux) - sx*inv;    // Lap feat 2pL
    float Ly = mf*bfhi(ux) - sy*inv;    // Lap feat 2pL+1

    // conv (no bias): out channels (2pL, 2pL+1), inputs = group-w feats via shfl
    float accx = 0.f, accy = 0.f;
    #pragma unroll
    for (int d = 0; d < 16; ++d) {
        int sl = w*16 + d;
        float ax = __shfl(Lx, sl);      // feat 32w+2d
        float ay = __shfl(Ly, sl);      // feat 32w+2d+1
        float2 wa = wc[(2*d)*16];       // W[w][2d][2jj..2jj+1]
        float2 wb = wc[(2*d+1)*16];
        accx = fmaf(ax, wa.x, accx); accx = fmaf(ay, wb.x, accx);
        accy = fmaf(ax, wa.y, accy); accy = fmaf(ay, wb.y, accy);
    }
    if (lane < 48) {
        float ox = fmaxf(accx + zr.x, 0.f);
        float oy = fmaxf(accy + zr.y, 0.f);
        *(uintT*)(rb2 + (size_t)t*96 + 2*pL) = pack2(ox, oy);
    }
}

// ---------- layer 3: out = widthmean(relu(Lap(rb2)@W_post + Zpost)), wave per node ----------
__global__ __launch_bounds__(256) void lap3(
    const ushortT* __restrict__ Xb,    // rb2 [N+1,96]
    const float*   __restrict__ Z,     // P + 288 (Zpost)
    const int* __restrict__ srcp, const int* __restrict__ src,
    const int* __restrict__ row_ptr,
    const float2* __restrict__ Wp2,    // [3][16][64] float2
    float* __restrict__ out)
{
    __shared__ float2 wS[3*16*64];
    int lane = threadIdx.x & 63;
    int t  = __builtin_amdgcn_readfirstlane((blockIdx.x << 2) + (threadIdx.x >> 6));
    int pL = lane < 48 ? lane : 0;
    // issue node-local loads first
    int sv = srcp[t*64 + lane];
    int lo = __builtin_amdgcn_readfirstlane(row_ptr[t]);
    int deg = __builtin_amdgcn_readfirstlane(row_ptr[t+1]) - lo;
    uintT ux = *(const uintT*)(Xb + (size_t)t*96 + 2*pL);
    float z0 = Z[(size_t)t*PCOLS + lane];
    float z1 = Z[(size_t)t*PCOLS + 64 + lane];
    float z2 = Z[(size_t)t*PCOLS + 128 + lane];

    for (int i = threadIdx.x; i < 3072; i += 256) wS[i] = Wp2[i];
    __syncthreads();

    const float2* wl = wS + lane;      // step 64 float2 per (w,i2)

    GATHER96(Xb, lo, deg, sv, pL, sx, sy)

    float inv = deg > 0 ? 1.f/(float)deg : 0.f;
    float mf  = deg > 0 ? 1.f : 0.f;
    float Lx = mf*bflo(ux) - sx*inv;
    float Ly = mf*bfhi(ux) - sy*inv;

    // conv: lane computes channels {L, 64+L, 128+L}; acts broadcast via readlane
    float a0 = 0.f, a1 = 0.f, a2 = 0.f;
    #pragma unroll
    for (int w2 = 0; w2 < 3; ++w2) {
        float acc = 0.f;
        #pragma unroll
        for (int i2 = 0; i2 < 16; ++i2) {
            float ax = rdlanef(Lx, 16*w2 + i2);   // feat 32w2+2i2
            float ay = rdlanef(Ly, 16*w2 + i2);   // feat 32w2+2i2+1
            float2 p = wl[(w2*16 + i2)*64];
            acc = fmaf(ax, p.x, acc);
            acc = fmaf(ay, p.y, acc);
        }
        if (w2 == 0) a0 = acc; else if (w2 == 1) a1 = acc; else a2 = acc;
    }
    float o0 = fmaxf(a0 + z0, 0.f);   // channel lane
    float o1 = fmaxf(a1 + z1, 0.f);   // channel 64+lane
    float o2 = fmaxf(a2 + z2, 0.f);   // channel 128+lane
    // width-mean: final[f] = (v(3f)+v(3f+1)+v(3f+2))/3, v(c) = o_{c>>6} @ lane c&63
    float r = 0.f;
    #pragma unroll
    for (int q = 0; q < 3; ++q) {
        int c = 3*lane + q;
        int sl = c & 63, wsel = c >> 6;
        float v0 = __shfl(o0, sl);
        float v1 = __shfl(o1, sl);
        float v2 = __shfl(o2, sl);
        r += (wsel == 0) ? v0 : ((wsel == 1) ? v1 : v2);
    }
    out[(size_t)t*64 + lane] = r * (1.0f/3.0f);
}

extern "C" void kernel_launch(void* const* d_in, const int* in_sizes, int n_in,
                              void* d_out, int out_size, void* d_ws, size_t ws_size,
                              hipStream_t stream)
{
    const float* data    = (const float*)d_in[0];
    const int*   src     = (const int*)  d_in[1];
    const int*   tgt     = (const int*)  d_in[2];
    const float* W_pre   = (const float*)d_in[3];
    const float* b_pre   = (const float*)d_in[4];
    const float* T_pre   = (const float*)d_in[5];
    const float* bT_pre  = (const float*)d_in[6];
    const float* W_blk   = (const float*)d_in[7];
    const float* b_blk   = (const float*)d_in[8];   // cancels under Lap — unused
    const float* T_blk   = (const float*)d_in[9];
    const float* bT_blk  = (const float*)d_in[10];
    const float* W_post  = (const float*)d_in[11];
    const float* b_post  = (const float*)d_in[12];  // cancels under Lap — unused
    const float* T_post  = (const float*)d_in[13];
    const float* bT_post = (const float*)d_in[14];
    float* out = (float*)d_out;

    float* ws = (float*)d_ws;
    float*   P       = ws;                                   // N*512 f32
    float*   bcat    = P + (size_t)N_NODES * PCOLS;          // 512
    float2*  Wp2     = (float2*)(bcat + 512);                // 3*16*64 float2
    int*     row_ptr = (int*)(Wp2 + 3*16*64);                // 50008
    int*     srcp    = row_ptr + 50008;                      // N*64
    ushortT* Y0b     = (ushortT*)(srcp + (size_t)N_NODES*64);   // (N+1)*96 bf16
    ushortT* rb1     = Y0b + (size_t)(N_NODES+1) * 96;          // (N+1)*96 bf16
    ushortT* rb2     = rb1 + (size_t)(N_NODES+1) * 96;          // (N+1)*96 bf16
    ushortT* Ab      = rb2 + (size_t)(N_NODES+1) * 96;          // N*128 bf16
    ushortT* Wb      = Ab  + (size_t)N_NODES * IN_F;            // 512*128 bf16

    // prep1: pack weights + convert data + row_ptr (fused, independent jobs)
    prep1<<<(N_NODES*IN_F/8)/256, 256, 0, stream>>>(
        data, W_pre, b_pre, T_pre, bT_pre, T_blk, bT_blk, T_post, bT_post,
        W_post, tgt, Wb, bcat, Wp2, Ab, row_ptr);

    build_srcp<<<(N_NODES*64)/256, 256, 0, stream>>>(src, row_ptr, srcp, Y0b, rb1, rb2);

    dim3 gg(PCOLS/128, (N_NODES + 127)/128);
    gemm_mfma<<<gg, 256, 0, stream>>>(Ab, Wb, bcat, P, Y0b, N_NODES);

    lap1<<<N_NODES/4, 256, 0, stream>>>(Y0b, P, P + 96, srcp, src, row_ptr, rb1);
    lap2<<<N_NODES/4, 256, 0, stream>>>(rb1, P + 192, srcp, src, row_ptr, W_blk, rb2);
    lap3<<<N_NODES/4, 256, 0, stream>>>(rb2, P + 288, srcp, src, row_ptr, Wp2, out);
}

// Round 12
// 302.566 us; speedup vs baseline: 1.9997x; 1.0051x over previous
//
#include <hip/hip_runtime.h>
#include <cstdint>
#include <cstddef>

#define N_NODES 50000
#define E_EDGES 800000
#define IN_F    128
#define PCOLS   512   // P: [0,96) Y0 | [96,192) Zpre | [192,288) Zblk | [288,480) Zpost | pad

typedef unsigned short ushortT;
typedef unsigned int   uintT;
typedef __attribute__((ext_vector_type(8))) short s8v;   // 8 bf16 (4 VGPR)
typedef __attribute__((ext_vector_type(4))) float f4v;   // 4 fp32 acc
typedef __attribute__((ext_vector_type(2))) float f2v;   // packed fp32 pair (v_pk_add_f32 target)

__device__ __forceinline__ float bflo(uintT u){ union{uintT i;float f;}c; c.i=u<<16; return c.f; }
__device__ __forceinline__ float bfhi(uintT u){ union{uintT i;float f;}c; c.i=u&0xFFFF0000u; return c.f; }
__device__ __forceinline__ ushortT f2bfu(float f){
    union{float f;uintT u;}c; c.f=f;
    uintT r = c.u + 0x7FFF + ((c.u>>16)&1);
    return (ushortT)(r>>16);
}
__device__ __forceinline__ uintT pack2(float a, float b){
    return (uintT)f2bfu(a) | ((uintT)f2bfu(b) << 16);
}

// ---------- prep1: pack weights + convert data + row_ptr (all independent) ----------
// grid = 800000 threads exactly (N*IN_F/8)
__global__ void prep1(const float* __restrict__ A,
                      const float* __restrict__ Wp,  const float* __restrict__ bp,
                      const float* __restrict__ Tp,  const float* __restrict__ bTp,
                      const float* __restrict__ Tb,  const float* __restrict__ bTb,
                      const float* __restrict__ Tpo, const float* __restrict__ bTpo,
                      const float* __restrict__ Wpost,
                      const int* __restrict__ tgt,
                      ushortT* __restrict__ Wb, float* __restrict__ bcat,
                      float2* __restrict__ Wp2,
                      ushortT* __restrict__ Ab, int* __restrict__ row_ptr)
{
    int gid = blockIdx.x * 256 + threadIdx.x;
    {
        size_t off = (size_t)gid * 8;
        float4 v0 = *(const float4*)(A + off);
        float4 v1 = *(const float4*)(A + off + 4);
        uint4 u;
        u.x = pack2(v0.x, v0.y); u.y = pack2(v0.z, v0.w);
        u.z = pack2(v1.x, v1.y); u.w = pack2(v1.z, v1.w);
        *(uint4*)(Ab + off) = u;
    }
    if (gid < IN_F * PCOLS) {
        int k = gid >> 9;
        int c = gid & 511;
        float v;
        if      (c < 96)  v = Wp [k*96  + c];
        else if (c < 192) v = Tp [k*96  + (c-96)];
        else if (c < 288) v = Tb [k*96  + (c-192)];
        else if (c < 480) v = Tpo[k*192 + (c-288)];
        else              v = 0.f;
        Wb[(size_t)c*IN_F + k] = f2bfu(v);
        if (k == 0) {
            float b;
            if      (c < 96)  b = bp  [c];
            else if (c < 192) b = bTp [c-96];
            else if (c < 288) b = bTb [c-192];
            else if (c < 480) b = bTpo[c-288];
            else              b = 0.f;
            bcat[c] = b;
        }
        if (gid < 3*16*64) {   // Wp2[(w*16+i2)*64+j] = (Wpost[w][2i2][j], Wpost[w][2i2+1][j])
            int w = gid >> 10, r = gid & 1023;
            int i2 = r >> 6, j = r & 63;
            Wp2[gid] = make_float2(Wpost[(w*32 + 2*i2)*64 + j],
                                   Wpost[(w*32 + 2*i2 + 1)*64 + j]);
        }
    }
    if (gid <= N_NODES) {
        int lo = 0, hi = E_EDGES;
        while (lo < hi) {
            int mid = (lo + hi) >> 1;
            if (tgt[mid] < gid) lo = mid + 1; else hi = mid;
        }
        row_ptr[gid] = lo;
    }
}

// ---------- srcp[t][slot] = BYTE offset of gather row (192 B rows); dummy -> row N ----------
__global__ void build_srcp(const int* __restrict__ src, const int* __restrict__ row_ptr,
                           int* __restrict__ srcp,
                           ushortT* __restrict__ Y0b, ushortT* __restrict__ rb1,
                           ushortT* __restrict__ rb2)
{
    int gid = blockIdx.x * 256 + threadIdx.x;   // N*64 threads
    int t = gid >> 6, slot = gid & 63;
    int lo = row_ptr[t];
    int deg = row_ptr[t+1] - lo;
    int v = slot < deg ? src[lo + slot] : N_NODES;
    srcp[gid] = v * 192;                        // pre-scaled: row stride 96 bf16 = 192 B
    if (gid < 96) {
        Y0b[(size_t)N_NODES*96 + gid] = 0;
        rb1[(size_t)N_NODES*96 + gid] = 0;
        rb2[(size_t)N_NODES*96 + gid] = 0;
    }
}

// ---------- MFMA GEMM: P[M,512] = Ab[M,128] @ Wb^T + bcat ; also emit Y0b bf16 ----------
__global__ __launch_bounds__(256, 2) void gemm_mfma(const ushortT* __restrict__ Ab,
                                                    const ushortT* __restrict__ Wb,
                                                    const float* __restrict__ bcat,
                                                    float* __restrict__ P,
                                                    ushortT* __restrict__ Y0b, int M)
{
    __shared__ ushortT Asl[128][72];
    __shared__ ushortT Bsl[128][72];
    int tid = threadIdx.x;
    int nb = blockIdx.x * 128;
    int mb = blockIdx.y * 128;
    int wv = tid >> 6, lane = tid & 63;
    int wm = wv >> 1, wn = wv & 1;
    int cl = lane & 15, q = lane >> 4;

    f4v acc[4][4];
    #pragma unroll
    for (int i = 0; i < 4; ++i)
        #pragma unroll
        for (int j = 0; j < 4; ++j) acc[i][j] = (f4v)0.f;

    for (int kt = 0; kt < IN_F; kt += 64) {
        if (kt) __syncthreads();
        #pragma unroll
        for (int r = 0; r < 4; ++r) {
            int idx = tid + 256*r;
            int row = idx >> 3, qq = idx & 7;
            int gm = mb + row;
            uint4 v = make_uint4(0,0,0,0);
            if (gm < M) v = *(const uint4*)(Ab + (size_t)gm*IN_F + kt + qq*8);
            *(uint4*)(&Asl[row][qq*8]) = v;
        }
        #pragma unroll
        for (int r = 0; r < 4; ++r) {
            int idx = tid + 256*r;
            int row = idx >> 3, qq = idx & 7;
            uint4 v = *(const uint4*)(Wb + (size_t)(nb+row)*IN_F + kt + qq*8);
            *(uint4*)(&Bsl[row][qq*8]) = v;
        }
        __syncthreads();
        #pragma unroll
        for (int ks = 0; ks < 2; ++ks) {
            int ko = ks*32 + q*8;
            s8v af[4], bf[4];
            #pragma unroll
            for (int mt = 0; mt < 4; ++mt)
                af[mt] = *(const s8v*)(&Asl[wm*64 + mt*16 + cl][ko]);
            #pragma unroll
            for (int nt = 0; nt < 4; ++nt)
                bf[nt] = *(const s8v*)(&Bsl[wn*64 + nt*16 + cl][ko]);
            #pragma unroll
            for (int mt = 0; mt < 4; ++mt)
                #pragma unroll
                for (int nt = 0; nt < 4; ++nt)
                    acc[mt][nt] = __builtin_amdgcn_mfma_f32_16x16x32_bf16(af[mt], bf[nt], acc[mt][nt], 0, 0, 0);
        }
    }

    bool y0blk = (nb == 0) && (wn == 0);
    #pragma unroll
    for (int nt = 0; nt < 4; ++nt) {
        int gn = nb + wn*64 + nt*16 + cl;
        float bv = bcat[gn];
        bool doY = y0blk && (gn < 96);
        #pragma unroll
        for (int mt = 0; mt < 4; ++mt) {
            int gm0 = mb + wm*64 + mt*16 + q*4;
            #pragma unroll
            for (int r = 0; r < 4; ++r) {
                int gm = gm0 + r;
                if (gm < M) {
                    float val = acc[mt][nt][r] + bv;
                    P[(size_t)gm*PCOLS + gn] = val;
                    if (doY) Y0b[(size_t)gm*96 + gn] = f2bfu(val);
                }
            }
        }
    }
}

// ===== gather core: 16-deep windows; scalar byte-offset addressing + packed adds =====
// srcp holds PRE-SCALED byte offsets (row*192). (Xb + off) is wave-uniform -> saddr form;
// 4*pL is the per-lane constant voffset.
#define GATHER96(Xb, lo, deg, sv, pL, sx, sy)                                     \
    float sx, sy;                                                                 \
    {                                                                             \
        f2v c0={0.f,0.f}, c1={0.f,0.f}, c2={0.f,0.f}, c3={0.f,0.f};               \
        int dmax = deg < 64 ? deg : 64;                                           \
        _Pragma("unroll 1")                                                       \
        for (int w_ = 0; w_ < dmax; w_ += 16) {                                   \
            uintT u[16];                                                          \
            _Pragma("unroll")                                                     \
            for (int kk = 0; kk < 16; ++kk) {                                     \
                int off = __builtin_amdgcn_readlane(sv, w_ + kk);                 \
                const char* rp = (const char*)(Xb) + off;                         \
                u[kk] = *(const uintT*)(rp + 4*pL);                               \
            }                                                                     \
            _Pragma("unroll")                                                     \
            for (int kk = 0; kk < 16; ++kk) {                                     \
                f2v v_; v_.x = bflo(u[kk]); v_.y = bfhi(u[kk]);                   \
                switch (kk & 3) {                                                 \
                    case 0: c0 += v_; break;                                      \
                    case 1: c1 += v_; break;                                      \
                    case 2: c2 += v_; break;                                      \
                    default:c3 += v_; break;                                      \
                }                                                                 \
            }                                                                     \
        }                                                                         \
        if (deg > 64) {                                                           \
            _Pragma("unroll 1")                                                   \
            for (int j_ = lo + 64; j_ < lo + deg; ++j_) {                         \
                int off = src[j_] * 192;                                          \
                const char* rp = (const char*)(Xb) + off;                         \
                uintT u0 = *(const uintT*)(rp + 4*pL);                            \
                f2v v_; v_.x = bflo(u0); v_.y = bfhi(u0);                         \
                c0 += v_;                                                         \
            }                                                                     \
        }                                                                         \
        f2v cs_ = (c0 + c1) + (c2 + c3);                                          \
        sx = cs_.x; sy = cs_.y;                                                   \
    }

// ---------- layer 1: rb1 = bf16(relu(Lap(Y0) + Zpre)), wave per node ----------
__global__ __launch_bounds__(256) void lap1(
    const ushortT* __restrict__ Xb,    // Y0b [N+1,96]
    const float*   __restrict__ Pown,  // P (cols 0..95 fp32 own-x)
    const float*   __restrict__ Z,     // P + 96
    const int* __restrict__ srcp, const int* __restrict__ src,
    const int* __restrict__ row_ptr,
    ushortT* __restrict__ rb1)
{
    int lane = threadIdx.x & 63;
    int t  = __builtin_amdgcn_readfirstlane((blockIdx.x << 2) + (threadIdx.x >> 6));
    int lo = __builtin_amdgcn_readfirstlane(row_ptr[t]);
    int deg = __builtin_amdgcn_readfirstlane(row_ptr[t+1]) - lo;
    int pL = lane < 48 ? lane : 0;
    int sv = srcp[t*64 + lane];
    float2 xr = *(const float2*)(Pown + (size_t)t*PCOLS + 2*pL);
    float2 zr = *(const float2*)(Z    + (size_t)t*PCOLS + 2*pL);

    GATHER96(Xb, lo, deg, sv, pL, sx, sy)

    float inv = deg > 0 ? 1.f/(float)deg : 0.f;
    float mf  = deg > 0 ? 1.f : 0.f;
    if (lane < 48) {
        float ox = fmaxf(mf*xr.x - sx*inv + zr.x, 0.f);
        float oy = fmaxf(mf*xr.y - sy*inv + zr.y, 0.f);
        *(uintT*)(rb1 + (size_t)t*96 + 2*pL) = pack2(ox, oy);
    }
}

// ---------- layer 2: rb2 = bf16(relu(Lap(rb1)@W_blk + Zblk)), wave per node ----------
__global__ __launch_bounds__(256) void lap2(
    const ushortT* __restrict__ Xb,    // rb1 [N+1,96]
    const float*   __restrict__ Z,     // P + 192 (Zblk)
    const int* __restrict__ srcp, const int* __restrict__ src,
    const int* __restrict__ row_ptr,
    const float* __restrict__ Wblk,    // [3][32][32] flat
    ushortT* __restrict__ rb2)
{
    __shared__ float wS[3*32*32];
    int lane = threadIdx.x & 63;
    int t  = __builtin_amdgcn_readfirstlane((blockIdx.x << 2) + (threadIdx.x >> 6));
    int pL = lane < 48 ? lane : 0;
    // node-local loads first; weight staging hides their latency
    int sv = srcp[t*64 + lane];
    int lo = __builtin_amdgcn_readfirstlane(row_ptr[t]);
    int deg = __builtin_amdgcn_readfirstlane(row_ptr[t+1]) - lo;
    uintT ux = *(const uintT*)(Xb + (size_t)t*96 + 2*pL);
    float2 zr = *(const float2*)(Z + (size_t)t*PCOLS + 2*pL);

    for (int i = threadIdx.x; i < 3072; i += 256) wS[i] = Wblk[i];
    __syncthreads();

    int w  = pL >> 4;            // group (uniform per 16-lane slab)
    int jj = pL & 15;            // out pair index within group
    const float2* wc = ((const float2*)wS) + (w*512 + jj);   // &W[w][0][2jj]

    GATHER96(Xb, lo, deg, sv, pL, sx, sy)

    float inv = deg > 0 ? 1.f/(float)deg : 0.f;
    float mf  = deg > 0 ? 1.f : 0.f;
    float Lx = mf*bflo(ux) - sx*inv;    // Lap feat 2pL
    float Ly = mf*bfhi(ux) - sy*inv;    // Lap feat 2pL+1

    // conv (no bias): out channels (2pL, 2pL+1), inputs = group-w feats via shfl
    float accx = 0.f, accy = 0.f;
    #pragma unroll
    for (int d = 0; d < 16; ++d) {
        int sl = w*16 + d;
        float ax = __shfl(Lx, sl);      // feat 32w+2d
        float ay = __shfl(Ly, sl);      // feat 32w+2d+1
        float2 wa = wc[(2*d)*16];       // W[w][2d][2jj..2jj+1]
        float2 wb = wc[(2*d+1)*16];
        accx = fmaf(ax, wa.x, accx); accx = fmaf(ay, wb.x, accx);
        accy = fmaf(ax, wa.y, accy); accy = fmaf(ay, wb.y, accy);
    }
    if (lane < 48) {
        float ox = fmaxf(accx + zr.x, 0.f);
        float oy = fmaxf(accy + zr.y, 0.f);
        *(uintT*)(rb2 + (size_t)t*96 + 2*pL) = pack2(ox, oy);
    }
}

// ---------- layer 3: out = widthmean(relu(Lap(rb2)@W_post + Zpost)), wave per node ----------
__global__ __launch_bounds__(256) void lap3(
    const ushortT* __restrict__ Xb,    // rb2 [N+1,96]
    const float*   __restrict__ Z,     // P + 288 (Zpost)
    const int* __restrict__ srcp, const int* __restrict__ src,
    const int* __restrict__ row_ptr,
    const float2* __restrict__ Wp2,    // [3][16][64] float2
    float* __restrict__ out)
{
    __shared__ float2 wS[3*16*64];
    __shared__ float  sm[4][96];       // per-wave activation slab (no barrier: wave DS in-order)
    int lane = threadIdx.x & 63;
    int wvw  = threadIdx.x >> 6;
    int t  = __builtin_amdgcn_readfirstlane((blockIdx.x << 2) + wvw);
    int pL = lane < 48 ? lane : 0;
    // node-local loads first
    int sv = srcp[t*64 + lane];
    int lo = __builtin_amdgcn_readfirstlane(row_ptr[t]);
    int deg = __builtin_amdgcn_readfirstlane(row_ptr[t+1]) - lo;
    uintT ux = *(const uintT*)(Xb + (size_t)t*96 + 2*pL);
    float z0 = Z[(size_t)t*PCOLS + lane];
    float z1 = Z[(size_t)t*PCOLS + 64 + lane];
    float z2 = Z[(size_t)t*PCOLS + 128 + lane];

    for (int i = threadIdx.x; i < 3072; i += 256) wS[i] = Wp2[i];
    __syncthreads();

    const float2* wl = wS + lane;      // step 64 float2 per (w,i2)

    GATHER96(Xb, lo, deg, sv, pL, sx, sy)

    float inv = deg > 0 ? 1.f/(float)deg : 0.f;
    float mf  = deg > 0 ? 1.f : 0.f;
    float Lx = mf*bflo(ux) - sx*inv;
    float Ly = mf*bfhi(ux) - sy*inv;

    // broadcast activations through per-wave LDS (uniform-address ds_read = broadcast)
    if (lane < 48) {
        sm[wvw][2*pL]     = Lx;
        sm[wvw][2*pL + 1] = Ly;
    }
    __builtin_amdgcn_wave_barrier();   // pin compiler order; wave DS ops are HW-in-order

    // conv: lane computes channels {L, 64+L, 128+L}
    float a0 = 0.f, a1 = 0.f, a2 = 0.f;
    #pragma unroll
    for (int w2 = 0; w2 < 3; ++w2) {
        float acc = 0.f;
        #pragma unroll
        for (int i2 = 0; i2 < 16; ++i2) {
            float2 iv = *(const float2*)(&sm[wvw][w2*32 + 2*i2]);   // broadcast read
            float2 p  = wl[(w2*16 + i2)*64];
            acc = fmaf(iv.x, p.x, acc);
            acc = fmaf(iv.y, p.y, acc);
        }
        if (w2 == 0) a0 = acc; else if (w2 == 1) a1 = acc; else a2 = acc;
    }
    float o0 = fmaxf(a0 + z0, 0.f);   // channel lane
    float o1 = fmaxf(a1 + z1, 0.f);   // channel 64+lane
    float o2 = fmaxf(a2 + z2, 0.f);   // channel 128+lane
    // width-mean: final[f] = (v(3f)+v(3f+1)+v(3f+2))/3, v(c) = o_{c>>6} @ lane c&63
    float r = 0.f;
    #pragma unroll
    for (int q = 0; q < 3; ++q) {
        int c = 3*lane + q;
        int sl = c & 63, wsel = c >> 6;
        float v0 = __shfl(o0, sl);
        float v1 = __shfl(o1, sl);
        float v2 = __shfl(o2, sl);
        r += (wsel == 0) ? v0 : ((wsel == 1) ? v1 : v2);
    }
    out[(size_t)t*64 + lane] = r * (1.0f/3.0f);
}

extern "C" void kernel_launch(void* const* d_in, const int* in_sizes, int n_in,
                              void* d_out, int out_size, void* d_ws, size_t ws_size,
                              hipStream_t stream)
{
    const float* data    = (const float*)d_in[0];
    const int*   src     = (const int*)  d_in[1];
    const int*   tgt     = (const int*)  d_in[2];
    const float* W_pre   = (const float*)d_in[3];
    const float* b_pre   = (const float*)d_in[4];
    const float* T_pre   = (const float*)d_in[5];
    const float* bT_pre  = (const float*)d_in[6];
    const float* W_blk   = (const float*)d_in[7];
    const float* b_blk   = (const float*)d_in[8];   // cancels under Lap — unused
    const float* T_blk   = (const float*)d_in[9];
    const float* bT_blk  = (const float*)d_in[10];
    const float* W_post  = (const float*)d_in[11];
    const float* b_post  = (const float*)d_in[12];  // cancels under Lap — unused
    const float* T_post  = (const float*)d_in[13];
    const float* bT_post = (const float*)d_in[14];
    float* out = (float*)d_out;

    float* ws = (float*)d_ws;
    float*   P       = ws;                                   // N*512 f32
    float*   bcat    = P + (size_t)N_NODES * PCOLS;          // 512
    float2*  Wp2     = (float2*)(bcat + 512);                // 3*16*64 float2
    int*     row_ptr = (int*)(Wp2 + 3*16*64);                // 50008
    int*     srcp    = row_ptr + 50008;                      // N*64 (byte offsets)
    ushortT* Y0b     = (ushortT*)(srcp + (size_t)N_NODES*64);   // (N+1)*96 bf16
    ushortT* rb1     = Y0b + (size_t)(N_NODES+1) * 96;          // (N+1)*96 bf16
    ushortT* rb2     = rb1 + (size_t)(N_NODES+1) * 96;          // (N+1)*96 bf16
    ushortT* Ab      = rb2 + (size_t)(N_NODES+1) * 96;          // N*128 bf16
    ushortT* Wb      = Ab  + (size_t)N_NODES * IN_F;            // 512*128 bf16

    prep1<<<(N_NODES*IN_F/8)/256, 256, 0, stream>>>(
        data, W_pre, b_pre, T_pre, bT_pre, T_blk, bT_blk, T_post, bT_post,
        W_post, tgt, Wb, bcat, Wp2, Ab, row_ptr);

    build_srcp<<<(N_NODES*64)/256, 256, 0, stream>>>(src, row_ptr, srcp, Y0b, rb1, rb2);

    dim3 gg(PCOLS/128, (N_NODES + 127)/128);
    gemm_mfma<<<gg, 256, 0, stream>>>(Ab, Wb, bcat, P, Y0b, N_NODES);

    lap1<<<N_NODES/4, 256, 0, stream>>>(Y0b, P, P + 96, srcp, src, row_ptr, rb1);
    lap2<<<N_NODES/4, 256, 0, stream>>>(rb1, P + 192, srcp, src, row_ptr, W_blk, rb2);
    lap3<<<N_NODES/4, 256, 0, stream>>>(rb2, P + 288, srcp, src, row_ptr, Wp2, out);
}